// Round 1
// baseline (1088.965 us; speedup 1.0000x reference)
//
#include <hip/hip_runtime.h>
#include <math.h>

#define Bb   4
#define Nn   4096
#define Mm   4096
#define Dd   256
#define D0c  128
#define Kc   64
#define TILE 128
#define BK   32

__device__ __forceinline__ unsigned encf(float f) {
    unsigned u = __float_as_uint(f);
    return (u & 0x80000000u) ? ~u : (u | 0x80000000u);
}
__device__ __forceinline__ float decf(unsigned u) {
    return (u & 0x80000000u) ? __uint_as_float(u ^ 0x80000000u) : __uint_as_float(~u);
}
__device__ __forceinline__ float softplusf(float x) {
    // matches jax.nn.softplus = logaddexp(x, 0)
    return fmaxf(x, 0.f) + log1pf(expf(-fabsf(x)));
}

// ---------------- norms: inv[row] = 1/||desc[row]|| ----------------
__global__ __launch_bounds__(256) void norm_kernel(
    const float* __restrict__ dA, const float* __restrict__ dB,
    float* __restrict__ invA, float* __restrict__ invB)
{
    const int t = threadIdx.x;
    const int wave = t >> 6, lane = t & 63;
    const int row = blockIdx.x * 4 + wave;          // 0..16383
    const float* src = (blockIdx.y == 0) ? dA : dB;
    float* dst       = (blockIdx.y == 0) ? invA : invB;
    const float4 v = *(const float4*)&src[(size_t)row * Dd + lane * 4];
    float ss = v.x * v.x + v.y * v.y + v.z * v.z + v.w * v.w;
#pragma unroll
    for (int m = 32; m; m >>= 1) ss += __shfl_xor(ss, m, 64);
    if (lane == 0) dst[row] = 1.0f / sqrtf(ss);
}

// ---------------- pass A: rowsum/colsum of exp(sim-20) ----------------
__global__ __launch_bounds__(256, 2) void simA_kernel(
    const float* __restrict__ descA, const float* __restrict__ descB,
    const float* __restrict__ invA, const float* __restrict__ invB,
    float* __restrict__ rowsumP, float* __restrict__ colsumP)
{
    __shared__ __align__(16) float As[BK][TILE];
    __shared__ __align__(16) float Bs[BK][TILE];
    __shared__ float colp[TILE];

    const int t  = threadIdx.x;
    const int mt = blockIdx.x, nt = blockIdx.y, bb = blockIdx.z;
    const int n0 = nt * TILE, m0 = mt * TILE;
    const int ty = t >> 4, tx = t & 15;

    if (t < TILE) colp[t] = 0.f;

    float acc[8][8];
#pragma unroll
    for (int i = 0; i < 8; i++)
#pragma unroll
        for (int j = 0; j < 8; j++) acc[i][j] = 0.f;

    const float* baseA = descA + (size_t)(bb * Nn + n0) * Dd;
    const float* baseB = descB + (size_t)(bb * Mm + m0) * Dd;
    const float* iA = invA + bb * Nn + n0;
    const float* iB = invB + bb * Mm + m0;

    for (int kc = 0; kc < Dd; kc += BK) {
#pragma unroll
        for (int i = 0; i < 4; i++) {
            int idx = t + i * 256;
            int r = idx >> 3, kq = idx & 7;
            float4 va = *(const float4*)&baseA[(size_t)r * Dd + kc + kq * 4];
            float sa = iA[r];
            As[kq * 4 + 0][r] = va.x * sa; As[kq * 4 + 1][r] = va.y * sa;
            As[kq * 4 + 2][r] = va.z * sa; As[kq * 4 + 3][r] = va.w * sa;
            float4 vb = *(const float4*)&baseB[(size_t)r * Dd + kc + kq * 4];
            float sb = iB[r];
            Bs[kq * 4 + 0][r] = vb.x * sb; Bs[kq * 4 + 1][r] = vb.y * sb;
            Bs[kq * 4 + 2][r] = vb.z * sb; Bs[kq * 4 + 3][r] = vb.w * sb;
        }
        __syncthreads();
#pragma unroll 4
        for (int kk = 0; kk < BK; ++kk) {
            float a[8], b[8];
            *(float4*)&a[0] = *(const float4*)&As[kk][ty * 8];
            *(float4*)&a[4] = *(const float4*)&As[kk][ty * 8 + 4];
            *(float4*)&b[0] = *(const float4*)&Bs[kk][tx * 8];
            *(float4*)&b[4] = *(const float4*)&Bs[kk][tx * 8 + 4];
#pragma unroll
            for (int i = 0; i < 8; i++)
#pragma unroll
                for (int j = 0; j < 8; j++) acc[i][j] = fmaf(a[i], b[j], acc[i][j]);
        }
        __syncthreads();
    }

    // epilogue: E = exp(20*dot - 20); partial row/col sums
    float rowpart[8], colpart[8];
#pragma unroll
    for (int i = 0; i < 8; i++) rowpart[i] = 0.f;
#pragma unroll
    for (int j = 0; j < 8; j++) colpart[j] = 0.f;
#pragma unroll
    for (int i = 0; i < 8; i++) {
#pragma unroll
        for (int j = 0; j < 8; j++) {
            float e = expf(fmaf(20.f, acc[i][j], -20.f));
            rowpart[i] += e;
            colpart[j] += e;
        }
    }
    // rows: reduce across the 16 tx lanes (same wave)
#pragma unroll
    for (int i = 0; i < 8; i++) {
#pragma unroll
        for (int m = 1; m < 16; m <<= 1) rowpart[i] += __shfl_xor(rowpart[i], m, 64);
    }
    if (tx == 0) {
#pragma unroll
        for (int i = 0; i < 8; i++)
            rowsumP[(size_t)(bb * 32 + mt) * Nn + n0 + ty * 8 + i] = rowpart[i];
    }
    // cols: reduce ty within wave, then LDS atomic across waves
#pragma unroll
    for (int j = 0; j < 8; j++) {
        colpart[j] += __shfl_xor(colpart[j], 16, 64);
        colpart[j] += __shfl_xor(colpart[j], 32, 64);
    }
    __syncthreads();
    if ((ty & 3) == 0) {
#pragma unroll
        for (int j = 0; j < 8; j++) atomicAdd(&colp[tx * 8 + j], colpart[j]);
    }
    __syncthreads();
    if (t < TILE) colsumP[(size_t)(bb * 32 + nt) * Mm + m0 + t] = colp[t];
}

// ---------------- reduce partials -> L = log(rowsum), Lc = log(colsum) ----------------
__global__ __launch_bounds__(256) void logsum_kernel(
    const float* __restrict__ rowsumP, const float* __restrict__ colsumP,
    float* __restrict__ Lrow, float* __restrict__ Lcol)
{
    int t = blockIdx.x * 256 + threadIdx.x;   // 0..32767
    int which = t >> 14;
    int idx = t & 16383;
    int bb = idx >> 12, n = idx & 4095;
    const float* P = which ? colsumP : rowsumP;
    float s = 0.f;
    for (int mt = 0; mt < 32; ++mt) s += P[(size_t)(bb * 32 + mt) * 4096 + n];
    (which ? Lcol : Lrow)[idx] = logf(s);
}

// ---------------- pass B: row argmax of logP, col max of cv ----------------
__global__ __launch_bounds__(256, 2) void simB_kernel(
    const float* __restrict__ descA, const float* __restrict__ descB,
    const float* __restrict__ invA, const float* __restrict__ invB,
    const float* __restrict__ Lrow_g, const float* __restrict__ Lcol_g,
    float* __restrict__ rkey, int* __restrict__ rmArr, float* __restrict__ rcvArr,
    unsigned* __restrict__ cmU)
{
    __shared__ __align__(16) float As[BK][TILE];
    __shared__ __align__(16) float Bs[BK][TILE];
    __shared__ unsigned colu[TILE];

    const int t  = threadIdx.x;
    const int mt = blockIdx.x, nt = blockIdx.y, bb = blockIdx.z;
    const int n0 = nt * TILE, m0 = mt * TILE;
    const int ty = t >> 4, tx = t & 15;

    if (t < TILE) colu[t] = 0u;

    float acc[8][8];
#pragma unroll
    for (int i = 0; i < 8; i++)
#pragma unroll
        for (int j = 0; j < 8; j++) acc[i][j] = 0.f;

    const float* baseA = descA + (size_t)(bb * Nn + n0) * Dd;
    const float* baseB = descB + (size_t)(bb * Mm + m0) * Dd;
    const float* iA = invA + bb * Nn + n0;
    const float* iB = invB + bb * Mm + m0;

    for (int kc = 0; kc < Dd; kc += BK) {
#pragma unroll
        for (int i = 0; i < 4; i++) {
            int idx = t + i * 256;
            int r = idx >> 3, kq = idx & 7;
            float4 va = *(const float4*)&baseA[(size_t)r * Dd + kc + kq * 4];
            float sa = iA[r];
            As[kq * 4 + 0][r] = va.x * sa; As[kq * 4 + 1][r] = va.y * sa;
            As[kq * 4 + 2][r] = va.z * sa; As[kq * 4 + 3][r] = va.w * sa;
            float4 vb = *(const float4*)&baseB[(size_t)r * Dd + kc + kq * 4];
            float sb = iB[r];
            Bs[kq * 4 + 0][r] = vb.x * sb; Bs[kq * 4 + 1][r] = vb.y * sb;
            Bs[kq * 4 + 2][r] = vb.z * sb; Bs[kq * 4 + 3][r] = vb.w * sb;
        }
        __syncthreads();
#pragma unroll 4
        for (int kk = 0; kk < BK; ++kk) {
            float a[8], b[8];
            *(float4*)&a[0] = *(const float4*)&As[kk][ty * 8];
            *(float4*)&a[4] = *(const float4*)&As[kk][ty * 8 + 4];
            *(float4*)&b[0] = *(const float4*)&Bs[kk][tx * 8];
            *(float4*)&b[4] = *(const float4*)&Bs[kk][tx * 8 + 4];
#pragma unroll
            for (int i = 0; i < 8; i++)
#pragma unroll
                for (int j = 0; j < 8; j++) acc[i][j] = fmaf(a[i], b[j], acc[i][j]);
        }
        __syncthreads();
    }

    // epilogue
    float Lr[8], Lc8[8];
#pragma unroll
    for (int i = 0; i < 8; i++) Lr[i] = Lrow_g[bb * Nn + n0 + ty * 8 + i];
#pragma unroll
    for (int j = 0; j < 8; j++) Lc8[j] = Lcol_g[bb * Mm + m0 + tx * 8 + j];

    float bk[8], bc[8];
    int bm[8];
    unsigned cu[8];
#pragma unroll
    for (int i = 0; i < 8; i++) { bk[i] = -INFINITY; bc[i] = -INFINITY; bm[i] = 0x7fffffff; }
#pragma unroll
    for (int j = 0; j < 8; j++) cu[j] = 0u;

#pragma unroll
    for (int i = 0; i < 8; i++) {
        const float ci = -40.f - Lr[i];
#pragma unroll
        for (int j = 0; j < 8; j++) {
            float cv = fmaf(40.f, acc[i][j], ci);    // 2*sim - 40 - L[n]
            float kv = cv - Lc8[j];                  // logP
            if (kv > bk[i]) { bk[i] = kv; bm[i] = m0 + tx * 8 + j; bc[i] = cv; }
            unsigned e = encf(cv);
            if (e > cu[j]) cu[j] = e;
        }
    }
    // row argmax across tx lanes (lexicographic: kv desc, m asc)
#pragma unroll
    for (int i = 0; i < 8; i++) {
#pragma unroll
        for (int m = 1; m < 16; m <<= 1) {
            float okv = __shfl_xor(bk[i], m, 64);
            int   om  = __shfl_xor(bm[i], m, 64);
            float ocv = __shfl_xor(bc[i], m, 64);
            if (okv > bk[i] || (okv == bk[i] && om < bm[i])) { bk[i] = okv; bm[i] = om; bc[i] = ocv; }
        }
    }
    if (tx == 0) {
#pragma unroll
        for (int i = 0; i < 8; i++) {
            size_t idx = (size_t)(bb * 32 + mt) * Nn + n0 + ty * 8 + i;
            rkey[idx] = bk[i]; rmArr[idx] = bm[i]; rcvArr[idx] = bc[i];
        }
    }
    // col max: reduce ty within wave, then LDS atomic across waves
#pragma unroll
    for (int j = 0; j < 8; j++) {
        unsigned o = __shfl_xor(cu[j], 16, 64); if (o > cu[j]) cu[j] = o;
        o = __shfl_xor(cu[j], 32, 64); if (o > cu[j]) cu[j] = o;
    }
    __syncthreads();
    if ((ty & 3) == 0) {
#pragma unroll
        for (int j = 0; j < 8; j++) atomicMax(&colu[tx * 8 + j], cu[j]);
    }
    __syncthreads();
    if (t < TILE) cmU[(size_t)(bb * 32 + nt) * Mm + m0 + t] = colu[t];
}

// ---------------- finalize rows: j, valid1 ----------------
__global__ __launch_bounds__(256) void finalize_kernel(
    const float* __restrict__ rkey, const int* __restrict__ rmArr,
    const float* __restrict__ rcvArr, const unsigned* __restrict__ cmU,
    float* __restrict__ outJ, int* __restrict__ jIdx, int* __restrict__ v1)
{
    const float LOG_THR = -4.605170185988091f;   // ln(0.01)
    int p = blockIdx.x * 256 + threadIdx.x;      // 0..16383
    int bb = p >> 12, n = p & 4095;
    float bk = -INFINITY, bc = -INFINITY;
    int bm = 0;
    for (int mt = 0; mt < 32; ++mt) {
        size_t idx = (size_t)(bb * 32 + mt) * Nn + n;
        float k = rkey[idx];
        if (k > bk) { bk = k; bm = rmArr[idx]; bc = rcvArr[idx]; }
    }
    unsigned u = 0u;
    for (int nt = 0; nt < 32; ++nt) {
        unsigned c = cmU[(size_t)(bb * 32 + nt) * Mm + bm];
        if (c > u) u = c;
    }
    float cm = decf(u);
    int ok = (bk > LOG_THR) && (bc >= cm);
    outJ[p] = (float)bm;
    jIdx[p] = bm;
    v1[p]   = ok;
}

// ---------------- affine head: per-point weighted lstsq + 2x2 SVD gate ----------------
__global__ __launch_bounds__(64) void affine_kernel(
    const float* __restrict__ descA, const float* __restrict__ descB,
    const float* __restrict__ kpA, const float* __restrict__ kpB,
    const float* __restrict__ W, const float* __restrict__ bvec,
    const int* __restrict__ jIdx, const int* __restrict__ v1,
    float* __restrict__ outA, float* __restrict__ outB, float* __restrict__ outV)
{
    __shared__ float Ws[D0c * Kc];          // 32 KB
    __shared__ float s0A[D0c], s1A[D0c], s0B[D0c], s1B[D0c];
    const int t = threadIdx.x;              // 0..63  (k index)
    for (int i = 0; i < 128; i++) Ws[i * 64 + t] = W[i * 64 + t];
    const float bl = bvec[t];
    __syncthreads();

    for (int p = 0; p < 32; ++p) {
        const int point = blockIdx.x * 32 + p;
        const int bb = point >> 12;
        const int j = jIdx[point];
        const float* da = descA + (size_t)point * Dd;
        const float* db = descB + (size_t)(bb * Mm + j) * Dd;
        s0A[t] = da[t];       s0A[64 + t] = da[64 + t];
        s1A[t] = da[128 + t]; s1A[64 + t] = da[192 + t];
        s0B[t] = db[t];       s0B[64 + t] = db[64 + t];
        s1B[t] = db[128 + t]; s1B[64 + t] = db[192 + t];
        __syncthreads();

        float xa = bl, xb = bl;
#pragma unroll 8
        for (int d = 0; d < 128; ++d) {
            float w_ = Ws[d * 64 + t];
            xa = fmaf(s0A[d], w_, xa);
            xb = fmaf(s0B[d], w_, xb);
        }
        float wa = softplusf(xa), wb = softplusf(xb);
        float w = sqrtf(wa * wb);
        float x0 = s1A[2 * t], x1 = s1A[2 * t + 1];
        float y0 = s1B[2 * t], y1 = s1B[2 * t + 1];
        float g00 = w * x0 * x0, g01 = w * x0 * x1, g11 = w * x1 * x1;
        float c00 = w * y0 * x0, c01 = w * y0 * x1;
        float c10 = w * y1 * x0, c11 = w * y1 * x1;
#pragma unroll
        for (int m = 32; m; m >>= 1) {
            g00 += __shfl_xor(g00, m, 64); g01 += __shfl_xor(g01, m, 64); g11 += __shfl_xor(g11, m, 64);
            c00 += __shfl_xor(c00, m, 64); c01 += __shfl_xor(c01, m, 64);
            c10 += __shfl_xor(c10, m, 64); c11 += __shfl_xor(c11, m, 64);
        }
        if (t == 0) {
            g00 += 1e-6f; g11 += 1e-6f;
            float det = g00 * g11 - g01 * g01;
            float e00 = (c00 * g11 - c01 * g01) / det;
            float e01 = (c01 * g00 - c00 * g01) / det;
            float e10 = (c10 * g11 - c11 * g01) / det;
            float e11 = (c11 * g00 - c10 * g01) / det;
            float m00 = e00 * e00 + e10 * e10;
            float m01 = e00 * e01 + e10 * e11;
            float m11 = e01 * e01 + e11 * e11;
            float tr = m00 + m11;
            float dm = m00 * m11 - m01 * m01;
            float disc = sqrtf(fmaxf(0.25f * tr * tr - dm, 0.f));
            float lhi = 0.5f * tr + disc;
            float llo = fmaxf(0.5f * tr - disc, 0.f);
            float shi = sqrtf(lhi), slo = sqrtf(llo);
            float sdet = e00 * e11 - e01 * e10;
            int good = isfinite(shi + slo) && (shi < 3.0f) && (slo > 0.33333334f) && (sdet > 0.f);
            int valid = v1[point] && good;
            outA[2 * point]     = kpA[2 * point];
            outA[2 * point + 1] = kpA[2 * point + 1];
            const float* kb = kpB + (size_t)(bb * Mm + j) * 2;
            outB[2 * point]     = kb[0];
            outB[2 * point + 1] = kb[1];
            outV[point] = valid ? 1.f : 0.f;
        }
        __syncthreads();
    }
}

extern "C" void kernel_launch(void* const* d_in, const int* in_sizes, int n_in,
                              void* d_out, int out_size, void* d_ws, size_t ws_size,
                              hipStream_t stream) {
    const float* kpA = (const float*)d_in[0];
    const float* dA  = (const float*)d_in[1];
    const float* kpB = (const float*)d_in[2];
    const float* dB  = (const float*)d_in[3];
    const float* W   = (const float*)d_in[4];
    const float* bl  = (const float*)d_in[5];
    float* out = (float*)d_out;

    char* ws = (char*)d_ws;
    float*    invA    = (float*)ws;              ws += 65536;
    float*    invB    = (float*)ws;              ws += 65536;
    float*    Lrow    = (float*)ws;              ws += 65536;
    float*    Lcol    = (float*)ws;              ws += 65536;
    int*      jIdx    = (int*)ws;                ws += 65536;
    int*      v1      = (int*)ws;                ws += 65536;
    float*    rowsumP = (float*)ws;              ws += 2097152;
    float*    colsumP = (float*)ws;              ws += 2097152;
    float*    rkey    = (float*)ws;              ws += 2097152;
    int*      rmArr   = (int*)ws;                ws += 2097152;
    float*    rcvArr  = (float*)ws;              ws += 2097152;
    unsigned* cmU     = (unsigned*)ws;           ws += 2097152;

    float* outA = out;               // matches_A : 32768
    float* outB = out + 32768;       // matches_B : 32768
    float* outJ = out + 65536;       // j (as f32): 16384
    float* outV = out + 81920;       // valid     : 16384

    norm_kernel<<<dim3(4096, 2), 256, 0, stream>>>(dA, dB, invA, invB);
    simA_kernel<<<dim3(32, 32, Bb), 256, 0, stream>>>(dA, dB, invA, invB, rowsumP, colsumP);
    logsum_kernel<<<128, 256, 0, stream>>>(rowsumP, colsumP, Lrow, Lcol);
    simB_kernel<<<dim3(32, 32, Bb), 256, 0, stream>>>(dA, dB, invA, invB, Lrow, Lcol,
                                                      rkey, rmArr, rcvArr, cmU);
    finalize_kernel<<<64, 256, 0, stream>>>(rkey, rmArr, rcvArr, cmU, outJ, jIdx, v1);
    affine_kernel<<<512, 64, 0, stream>>>(dA, dB, kpA, kpB, W, bl, jIdx, v1, outA, outB, outV);
}

// Round 2
// 971.440 us; speedup vs baseline: 1.1210x; 1.1210x over previous
//
#include <hip/hip_runtime.h>
#include <math.h>

#define Bb   4
#define Nn   4096
#define Mm   4096
#define Dd   256
#define D0c  128
#define Kc   64

typedef _Float16 half8 __attribute__((ext_vector_type(8)));
typedef float    f32x4 __attribute__((ext_vector_type(4)));

__device__ __forceinline__ unsigned encf(float f) {
    unsigned u = __float_as_uint(f);
    return (u & 0x80000000u) ? ~u : (u | 0x80000000u);
}
__device__ __forceinline__ float decf(unsigned u) {
    return (u & 0x80000000u) ? __uint_as_float(u ^ 0x80000000u) : __uint_as_float(~u);
}
__device__ __forceinline__ float softplusf(float x) {
    return fmaxf(x, 0.f) + log1pf(expf(-fabsf(x)));
}
__device__ __forceinline__ void gl_lds16(const _Float16* g, _Float16* l) {
    __builtin_amdgcn_global_load_lds((const __attribute__((address_space(1))) void*)g,
                                     (__attribute__((address_space(3))) void*)l, 16, 0, 0);
}

// ---------------- prep: normalize rows, split to fp16 hi / scaled-lo ----------------
__global__ __launch_bounds__(256) void prep_kernel(
    const float* __restrict__ dA, const float* __restrict__ dB,
    _Float16* __restrict__ Ah, _Float16* __restrict__ Al,
    _Float16* __restrict__ Bh, _Float16* __restrict__ Bl)
{
    const int t = threadIdx.x, wave = t >> 6, lane = t & 63;
    const int row = blockIdx.x * 4 + wave;           // 0..16383
    const float* src = blockIdx.y ? dB : dA;
    _Float16* dh = blockIdx.y ? Bh : Ah;
    _Float16* dl = blockIdx.y ? Bl : Al;
    const float4 v = *(const float4*)&src[(size_t)row * Dd + lane * 4];
    float ss = v.x * v.x + v.y * v.y + v.z * v.z + v.w * v.w;
#pragma unroll
    for (int m = 32; m; m >>= 1) ss += __shfl_xor(ss, m, 64);
    const float inv = 1.0f / sqrtf(ss);
    float x[4] = {v.x * inv, v.y * inv, v.z * inv, v.w * inv};
    union { _Float16 h[4]; uint2 u; } ph, pl;
#pragma unroll
    for (int i = 0; i < 4; i++) {
        _Float16 h = (_Float16)x[i];
        ph.h[i] = h;
        pl.h[i] = (_Float16)((x[i] - (float)h) * 4096.f);
    }
    *(uint2*)&dh[(size_t)row * Dd + lane * 4] = ph.u;
    *(uint2*)&dl[(size_t)row * Dd + lane * 4] = pl.u;
}

// ---------------- MFMA sim kernel; PB=0: row/col sums of exp, PB=1: argmax pass ------
template<int PB>
__global__ __launch_bounds__(256) void sim_kernel(
    const _Float16* __restrict__ Ah, const _Float16* __restrict__ Al,
    const _Float16* __restrict__ Bh, const _Float16* __restrict__ Bl,
    const float* __restrict__ Lrow_g, const float* __restrict__ Lcol_g,
    float* __restrict__ rowsumP, float* __restrict__ colsumP,
    float* __restrict__ rkey, int* __restrict__ rmArr, float* __restrict__ rcvArr,
    unsigned* __restrict__ cmU)
{
    __shared__ _Float16 lds[4][4][128][8];   // [comp][koct][row][oct] = 32 KB
    __shared__ float    colp[128];
    __shared__ unsigned colu[128];
    __shared__ float    shL[128], shLc[128];

    const int t = threadIdx.x;
    const int wave = t >> 6, lane = t & 63;
    const int mt = blockIdx.x, nt = blockIdx.y, bb = blockIdx.z;
    const int n0 = nt * 128, m0 = mt * 128;

    if (PB) {
        if (t < 128) {
            shL[t]  = Lrow_g[bb * Nn + n0 + t];
            shLc[t] = Lcol_g[bb * Mm + m0 + t];
            colu[t] = 0u;
        }
    } else {
        if (t < 128) colp[t] = 0.f;
    }

    const _Float16* gb;
    {
        const size_t offA = (size_t)(bb * Nn + n0) * Dd;
        const size_t offB = (size_t)(bb * Mm + m0) * Dd;
        if      (wave == 0) gb = Ah + offA;
        else if (wave == 1) gb = Al + offA;
        else if (wave == 2) gb = Bh + offB;
        else                gb = Bl + offB;
    }

    f32x4 acc1[2][8], acc2[2][8];
#pragma unroll
    for (int ti = 0; ti < 2; ti++)
#pragma unroll
        for (int tj = 0; tj < 8; tj++) { acc1[ti][tj] = (f32x4)0.f; acc2[ti][tj] = (f32x4)0.f; }

    const int quad = lane >> 4, l15 = lane & 15;

    for (int kc = 0; kc < Dd; kc += 32) {
        // stage: wave w stages component w (128 rows x 32 k, fp16) via 8 x 1KB issues
#pragma unroll
        for (int q = 0; q < 8; ++q) {
            const int koct = q >> 1, r0 = (q & 1) * 64;
            gl_lds16(gb + (size_t)(r0 + lane) * Dd + kc + koct * 8, &lds[wave][koct][r0][0]);
        }
        __syncthreads();

        half8 afh[2], afl[2];
        afh[0] = *(const half8*)&lds[0][quad][wave * 32 + l15][0];
        afh[1] = *(const half8*)&lds[0][quad][wave * 32 + 16 + l15][0];
        afl[0] = *(const half8*)&lds[1][quad][wave * 32 + l15][0];
        afl[1] = *(const half8*)&lds[1][quad][wave * 32 + 16 + l15][0];
#pragma unroll
        for (int tj = 0; tj < 8; ++tj) {
            half8 bh = *(const half8*)&lds[2][quad][tj * 16 + l15][0];
            half8 bl = *(const half8*)&lds[3][quad][tj * 16 + l15][0];
#pragma unroll
            for (int ti = 0; ti < 2; ++ti) {
                acc1[ti][tj] = __builtin_amdgcn_mfma_f32_16x16x32_f16(afh[ti], bh, acc1[ti][tj], 0, 0, 0);
                acc2[ti][tj] = __builtin_amdgcn_mfma_f32_16x16x32_f16(afh[ti], bl, acc2[ti][tj], 0, 0, 0);
                acc2[ti][tj] = __builtin_amdgcn_mfma_f32_16x16x32_f16(afl[ti], bh, acc2[ti][tj], 0, 0, 0);
            }
        }
        __syncthreads();
    }

    // element (ti,tj,r): n_local = wave*32 + ti*16 + quad*4 + r ; m_local = tj*16 + l15
    if (!PB) {
        float rp[8] = {0.f}, cp[8] = {0.f};
#pragma unroll
        for (int ti = 0; ti < 2; ++ti)
#pragma unroll
            for (int tj = 0; tj < 8; ++tj)
#pragma unroll
                for (int r = 0; r < 4; ++r) {
                    float dot = fmaf(acc2[ti][tj][r], 2.44140625e-4f, acc1[ti][tj][r]);
                    float e = __expf(fmaf(20.f, dot, -20.f));
                    rp[ti * 4 + r] += e;
                    cp[tj] += e;
                }
#pragma unroll
        for (int i = 0; i < 8; ++i)
#pragma unroll
            for (int m = 1; m < 16; m <<= 1) rp[i] += __shfl_xor(rp[i], m, 64);
        if (l15 == 0) {
#pragma unroll
            for (int ti = 0; ti < 2; ++ti)
#pragma unroll
                for (int r = 0; r < 4; ++r)
                    rowsumP[(size_t)(bb * 32 + mt) * Nn + n0 + wave * 32 + ti * 16 + quad * 4 + r] = rp[ti * 4 + r];
        }
#pragma unroll
        for (int tj = 0; tj < 8; ++tj) {
            cp[tj] += __shfl_xor(cp[tj], 16, 64);
            cp[tj] += __shfl_xor(cp[tj], 32, 64);
        }
        if (quad == 0) {
#pragma unroll
            for (int tj = 0; tj < 8; ++tj) atomicAdd(&colp[tj * 16 + l15], cp[tj]);
        }
        __syncthreads();
        if (t < 128) colsumP[(size_t)(bb * 32 + nt) * Mm + m0 + t] = colp[t];
    } else {
        float Lr[8];
#pragma unroll
        for (int ti = 0; ti < 2; ++ti)
#pragma unroll
            for (int r = 0; r < 4; ++r)
                Lr[ti * 4 + r] = shL[wave * 32 + ti * 16 + quad * 4 + r];

        float bk[8], bc[8];
        int bm[8];
        unsigned cu[8];
#pragma unroll
        for (int i = 0; i < 8; i++) { bk[i] = -INFINITY; bc[i] = -INFINITY; bm[i] = 0x7fffffff; }
#pragma unroll
        for (int j = 0; j < 8; j++) cu[j] = 0u;

#pragma unroll
        for (int ti = 0; ti < 2; ++ti)
#pragma unroll
            for (int tj = 0; tj < 8; ++tj)
#pragma unroll
                for (int r = 0; r < 4; ++r) {
                    float dot = fmaf(acc2[ti][tj][r], 2.44140625e-4f, acc1[ti][tj][r]);
                    float cv = fmaf(40.f, dot, -40.f - Lr[ti * 4 + r]);
                    float kv = cv - shLc[tj * 16 + l15];
                    const int i = ti * 4 + r;
                    if (kv > bk[i]) { bk[i] = kv; bm[i] = m0 + tj * 16 + l15; bc[i] = cv; }
                    unsigned e = encf(cv);
                    if (e > cu[tj]) cu[tj] = e;
                }
#pragma unroll
        for (int i = 0; i < 8; ++i) {
#pragma unroll
            for (int m = 1; m < 16; m <<= 1) {
                float okv = __shfl_xor(bk[i], m, 64);
                int   om  = __shfl_xor(bm[i], m, 64);
                float ocv = __shfl_xor(bc[i], m, 64);
                if (okv > bk[i] || (okv == bk[i] && om < bm[i])) { bk[i] = okv; bm[i] = om; bc[i] = ocv; }
            }
        }
        if (l15 == 0) {
#pragma unroll
            for (int ti = 0; ti < 2; ++ti)
#pragma unroll
                for (int r = 0; r < 4; ++r) {
                    const int i = ti * 4 + r;
                    size_t idx = (size_t)(bb * 32 + mt) * Nn + n0 + wave * 32 + ti * 16 + quad * 4 + r;
                    rkey[idx] = bk[i]; rmArr[idx] = bm[i]; rcvArr[idx] = bc[i];
                }
        }
#pragma unroll
        for (int tj = 0; tj < 8; ++tj) {
            unsigned o = __shfl_xor(cu[tj], 16, 64); if (o > cu[tj]) cu[tj] = o;
            o = __shfl_xor(cu[tj], 32, 64); if (o > cu[tj]) cu[tj] = o;
        }
        if (quad == 0) {
#pragma unroll
            for (int tj = 0; tj < 8; ++tj) atomicMax(&colu[tj * 16 + l15], cu[tj]);
        }
        __syncthreads();
        if (t < 128) cmU[(size_t)(bb * 32 + nt) * Mm + m0 + t] = colu[t];
    }
}

// ---------------- reduce partials -> L = log(rowsum), Lc = log(colsum) ----------------
__global__ __launch_bounds__(256) void logsum_kernel(
    const float* __restrict__ rowsumP, const float* __restrict__ colsumP,
    float* __restrict__ Lrow, float* __restrict__ Lcol)
{
    int t = blockIdx.x * 256 + threadIdx.x;   // 0..32767
    int which = t >> 14;
    int idx = t & 16383;
    int bb = idx >> 12, n = idx & 4095;
    const float* P = which ? colsumP : rowsumP;
    float s = 0.f;
    for (int mt = 0; mt < 32; ++mt) s += P[(size_t)(bb * 32 + mt) * 4096 + n];
    (which ? Lcol : Lrow)[idx] = logf(s);
}

// ---------------- finalize rows: j, valid1 ----------------
__global__ __launch_bounds__(256) void finalize_kernel(
    const float* __restrict__ rkey, const int* __restrict__ rmArr,
    const float* __restrict__ rcvArr, const unsigned* __restrict__ cmU,
    float* __restrict__ outJ, int* __restrict__ jIdx, int* __restrict__ v1)
{
    const float LOG_THR = -4.605170185988091f;   // ln(0.01)
    int p = blockIdx.x * 256 + threadIdx.x;      // 0..16383
    int bb = p >> 12, n = p & 4095;
    float bk = -INFINITY, bc = -INFINITY;
    int bm = 0;
    for (int mt = 0; mt < 32; ++mt) {
        size_t idx = (size_t)(bb * 32 + mt) * Nn + n;
        float k = rkey[idx];
        if (k > bk) { bk = k; bm = rmArr[idx]; bc = rcvArr[idx]; }
    }
    unsigned u = 0u;
    for (int nt = 0; nt < 32; ++nt) {
        unsigned c = cmU[(size_t)(bb * 32 + nt) * Mm + bm];
        if (c > u) u = c;
    }
    float cm = decf(u);
    int ok = (bk > LOG_THR) && (bc >= cm);
    outJ[p] = (float)bm;
    jIdx[p] = bm;
    v1[p]   = ok;
}

// ---------------- affine head ----------------
__global__ __launch_bounds__(64) void affine_kernel(
    const float* __restrict__ descA, const float* __restrict__ descB,
    const float* __restrict__ kpA, const float* __restrict__ kpB,
    const float* __restrict__ W, const float* __restrict__ bvec,
    const int* __restrict__ jIdx, const int* __restrict__ v1,
    float* __restrict__ outA, float* __restrict__ outB, float* __restrict__ outV)
{
    __shared__ float Ws[D0c * Kc];          // 32 KB
    __shared__ float s0A[D0c], s1A[D0c], s0B[D0c], s1B[D0c];
    const int t = threadIdx.x;              // 0..63  (k index)
    for (int i = 0; i < 128; i++) Ws[i * 64 + t] = W[i * 64 + t];
    const float bl = bvec[t];
    __syncthreads();

    for (int p = 0; p < 32; ++p) {
        const int point = blockIdx.x * 32 + p;
        const int bb = point >> 12;
        const int j = jIdx[point];
        const float* da = descA + (size_t)point * Dd;
        const float* db = descB + (size_t)(bb * Mm + j) * Dd;
        s0A[t] = da[t];       s0A[64 + t] = da[64 + t];
        s1A[t] = da[128 + t]; s1A[64 + t] = da[192 + t];
        s0B[t] = db[t];       s0B[64 + t] = db[64 + t];
        s1B[t] = db[128 + t]; s1B[64 + t] = db[192 + t];
        __syncthreads();

        float xa = bl, xb = bl;
#pragma unroll 8
        for (int d = 0; d < 128; ++d) {
            float w_ = Ws[d * 64 + t];
            xa = fmaf(s0A[d], w_, xa);
            xb = fmaf(s0B[d], w_, xb);
        }
        float wa = softplusf(xa), wb = softplusf(xb);
        float w = sqrtf(wa * wb);
        float x0 = s1A[2 * t], x1 = s1A[2 * t + 1];
        float y0 = s1B[2 * t], y1 = s1B[2 * t + 1];
        float g00 = w * x0 * x0, g01 = w * x0 * x1, g11 = w * x1 * x1;
        float c00 = w * y0 * x0, c01 = w * y0 * x1;
        float c10 = w * y1 * x0, c11 = w * y1 * x1;
#pragma unroll
        for (int m = 32; m; m >>= 1) {
            g00 += __shfl_xor(g00, m, 64); g01 += __shfl_xor(g01, m, 64); g11 += __shfl_xor(g11, m, 64);
            c00 += __shfl_xor(c00, m, 64); c01 += __shfl_xor(c01, m, 64);
            c10 += __shfl_xor(c10, m, 64); c11 += __shfl_xor(c11, m, 64);
        }
        if (t == 0) {
            g00 += 1e-6f; g11 += 1e-6f;
            float det = g00 * g11 - g01 * g01;
            float e00 = (c00 * g11 - c01 * g01) / det;
            float e01 = (c01 * g00 - c00 * g01) / det;
            float e10 = (c10 * g11 - c11 * g01) / det;
            float e11 = (c11 * g00 - c10 * g01) / det;
            float m00 = e00 * e00 + e10 * e10;
            float m01 = e00 * e01 + e10 * e11;
            float m11 = e01 * e01 + e11 * e11;
            float tr = m00 + m11;
            float dm = m00 * m11 - m01 * m01;
            float disc = sqrtf(fmaxf(0.25f * tr * tr - dm, 0.f));
            float lhi = 0.5f * tr + disc;
            float llo = fmaxf(0.5f * tr - disc, 0.f);
            float shi = sqrtf(lhi), slo = sqrtf(llo);
            float sdet = e00 * e11 - e01 * e10;
            int good = isfinite(shi + slo) && (shi < 3.0f) && (slo > 0.33333334f) && (sdet > 0.f);
            int valid = v1[point] && good;
            outA[2 * point]     = kpA[2 * point];
            outA[2 * point + 1] = kpA[2 * point + 1];
            const float* kb = kpB + (size_t)(bb * Mm + j) * 2;
            outB[2 * point]     = kb[0];
            outB[2 * point + 1] = kb[1];
            outV[point] = valid ? 1.f : 0.f;
        }
        __syncthreads();
    }
}

extern "C" void kernel_launch(void* const* d_in, const int* in_sizes, int n_in,
                              void* d_out, int out_size, void* d_ws, size_t ws_size,
                              hipStream_t stream) {
    const float* kpA = (const float*)d_in[0];
    const float* dA  = (const float*)d_in[1];
    const float* kpB = (const float*)d_in[2];
    const float* dB  = (const float*)d_in[3];
    const float* W   = (const float*)d_in[4];
    const float* bl  = (const float*)d_in[5];
    float* out = (float*)d_out;

    char* ws = (char*)d_ws;
    _Float16* Ah = (_Float16*)ws;  ws += 8388608;
    _Float16* Al = (_Float16*)ws;  ws += 8388608;
    _Float16* Bh = (_Float16*)ws;  ws += 8388608;
    _Float16* Bl = (_Float16*)ws;  ws += 8388608;
    float*    rowsumP = (float*)ws;    ws += 2097152;
    float*    colsumP = (float*)ws;    ws += 2097152;
    float*    rkey    = (float*)ws;    ws += 2097152;
    int*      rmArr   = (int*)ws;      ws += 2097152;
    float*    rcvArr  = (float*)ws;    ws += 2097152;
    unsigned* cmU     = (unsigned*)ws; ws += 2097152;
    float*    Lrow    = (float*)ws;    ws += 65536;
    float*    Lcol    = (float*)ws;    ws += 65536;
    int*      jIdx    = (int*)ws;      ws += 65536;
    int*      v1      = (int*)ws;      ws += 65536;

    float* outA = out;               // matches_A : 32768
    float* outB = out + 32768;       // matches_B : 32768
    float* outJ = out + 65536;       // j (as f32): 16384
    float* outV = out + 81920;       // valid     : 16384

    prep_kernel<<<dim3(4096, 2), 256, 0, stream>>>(dA, dB, Ah, Al, Bh, Bl);
    sim_kernel<0><<<dim3(32, 32, Bb), 256, 0, stream>>>(Ah, Al, Bh, Bl, nullptr, nullptr,
                                                        rowsumP, colsumP,
                                                        nullptr, nullptr, nullptr, nullptr);
    logsum_kernel<<<128, 256, 0, stream>>>(rowsumP, colsumP, Lrow, Lcol);
    sim_kernel<1><<<dim3(32, 32, Bb), 256, 0, stream>>>(Ah, Al, Bh, Bl, Lrow, Lcol,
                                                        nullptr, nullptr,
                                                        rkey, rmArr, rcvArr, cmU);
    finalize_kernel<<<64, 256, 0, stream>>>(rkey, rmArr, rcvArr, cmU, outJ, jIdx, v1);
    affine_kernel<<<512, 64, 0, stream>>>(dA, dB, kpA, kpB, W, bl, jIdx, v1, outA, outB, outV);
}

// Round 3
// 403.268 us; speedup vs baseline: 2.7003x; 2.4089x over previous
//
#include <hip/hip_runtime.h>
#include <math.h>

#define Bb   4
#define Nn   4096
#define Mm   4096
#define Dd   256
#define D0c  128
#define Kc   64

typedef _Float16 half8 __attribute__((ext_vector_type(8)));
typedef float    f32x4 __attribute__((ext_vector_type(4)));

__device__ __forceinline__ unsigned encf(float f) {
    unsigned u = __float_as_uint(f);
    return (u & 0x80000000u) ? ~u : (u | 0x80000000u);
}
__device__ __forceinline__ float decf(unsigned u) {
    return (u & 0x80000000u) ? __uint_as_float(u ^ 0x80000000u) : __uint_as_float(~u);
}
__device__ __forceinline__ float softplusf(float x) {
    return fmaxf(x, 0.f) + log1pf(expf(-fabsf(x)));
}
__device__ __forceinline__ void gl_lds16(const _Float16* g, _Float16* l) {
    __builtin_amdgcn_global_load_lds((const __attribute__((address_space(1))) void*)g,
                                     (__attribute__((address_space(3))) void*)l, 16, 0, 0);
}

// ---------------- prep: normalize rows, split fp16 hi/lo, write TILED layout -------
// Tiled layout per 128-row tile: 8 chunks of [koct(4)][row(128)][8 halves] = 8 KB each.
// Linear base of tile = (globalRow>>7)*32768 halves (tiles are contiguous).
__global__ __launch_bounds__(256) void prep_kernel(
    const float* __restrict__ dA, const float* __restrict__ dB,
    _Float16* __restrict__ Ah, _Float16* __restrict__ Al,
    _Float16* __restrict__ Bh, _Float16* __restrict__ Bl)
{
    const int t = threadIdx.x, wave = t >> 6, lane = t & 63;
    const int row = blockIdx.x * 4 + wave;           // 0..16383
    const float* src = blockIdx.y ? dB : dA;
    _Float16* dh = blockIdx.y ? Bh : Ah;
    _Float16* dl = blockIdx.y ? Bl : Al;
    const float4 v = *(const float4*)&src[(size_t)row * Dd + lane * 4];
    float ss = v.x * v.x + v.y * v.y + v.z * v.z + v.w * v.w;
#pragma unroll
    for (int m = 32; m; m >>= 1) ss += __shfl_xor(ss, m, 64);
    const float inv = 1.0f / sqrtf(ss);
    float x[4] = {v.x * inv, v.y * inv, v.z * inv, v.w * inv};
    union { _Float16 h[4]; uint2 u; } ph, pl;
#pragma unroll
    for (int i = 0; i < 4; i++) {
        _Float16 h = (_Float16)x[i];
        ph.h[i] = h;
        pl.h[i] = (_Float16)((x[i] - (float)h) * 4096.f);
    }
    // k0 = lane*4: chunk = lane>>3, koct = (lane>>1)&3, rem = (lane&1)*4
    const size_t toff = (size_t)(row >> 7) * 32768
                      + (size_t)(lane >> 3) * 4096
                      + (size_t)((lane >> 1) & 3) * 1024
                      + (size_t)(row & 127) * 8 + (lane & 1) * 4;
    *(uint2*)&dh[toff] = ph.u;
    *(uint2*)&dl[toff] = pl.u;
}

// ---------------- MFMA sim kernel; PB=0: row/col sums of exp, PB=1: argmax pass ------
template<int PB>
__global__ __launch_bounds__(256, 2) void sim_kernel(
    const _Float16* __restrict__ Ah, const _Float16* __restrict__ Al,
    const _Float16* __restrict__ Bh, const _Float16* __restrict__ Bl,
    const float* __restrict__ Lrow_g, const float* __restrict__ Lcol_g,
    float* __restrict__ rowsumP, float* __restrict__ colsumP,
    float* __restrict__ rkey, int* __restrict__ rmArr, float* __restrict__ rcvArr,
    unsigned* __restrict__ cmU)
{
    __shared__ _Float16 lds[4][4][128][8];   // [comp][koct][row][oct] = 32 KB
    __shared__ float    colp[128];
    __shared__ unsigned colu[128];
    __shared__ float    shL[128], shLc[128];

    const int t = threadIdx.x;
    const int wave = t >> 6, lane = t & 63;
    const int mt = blockIdx.x, nt = blockIdx.y, bb = blockIdx.z;
    const int n0 = nt * 128, m0 = mt * 128;

    if (PB) {
        if (t < 128) {
            shL[t]  = Lrow_g[bb * Nn + n0 + t];
            shLc[t] = Lcol_g[bb * Mm + m0 + t];
            colu[t] = 0u;
        }
    } else {
        if (t < 128) colp[t] = 0.f;
    }

    // per-wave component base (tiled layout: tile base = linear row offset * Dd)
    const _Float16* gb;
    {
        const size_t offA = (size_t)(bb * Nn + n0) * Dd;
        const size_t offB = (size_t)(bb * Mm + m0) * Dd;
        if      (wave == 0) gb = Ah + offA;
        else if (wave == 1) gb = Al + offA;
        else if (wave == 2) gb = Bh + offB;
        else                gb = Bl + offB;
    }

    f32x4 acc1[2][8], acc2[2][8];
#pragma unroll
    for (int ti = 0; ti < 2; ti++)
#pragma unroll
        for (int tj = 0; tj < 8; tj++) { acc1[ti][tj] = (f32x4)0.f; acc2[ti][tj] = (f32x4)0.f; }

    const int quad = lane >> 4, l15 = lane & 15;
    _Float16* ldsw = &lds[wave][0][0][0];

    for (int kc8 = 0; kc8 < 8; ++kc8) {
        // stage: wave w stages component w, 8 KB contiguous = 8 x 1KB coalesced issues
        const _Float16* gsrc = gb + kc8 * 4096;
#pragma unroll
        for (int q = 0; q < 8; ++q)
            gl_lds16(gsrc + q * 512 + lane * 8, ldsw + q * 512);
        __syncthreads();

        half8 afh[2], afl[2];
        afh[0] = *(const half8*)&lds[0][quad][wave * 32 + l15][0];
        afh[1] = *(const half8*)&lds[0][quad][wave * 32 + 16 + l15][0];
        afl[0] = *(const half8*)&lds[1][quad][wave * 32 + l15][0];
        afl[1] = *(const half8*)&lds[1][quad][wave * 32 + 16 + l15][0];
#pragma unroll
        for (int tj = 0; tj < 8; ++tj) {
            half8 bh = *(const half8*)&lds[2][quad][tj * 16 + l15][0];
            half8 bl = *(const half8*)&lds[3][quad][tj * 16 + l15][0];
#pragma unroll
            for (int ti = 0; ti < 2; ++ti) {
                acc1[ti][tj] = __builtin_amdgcn_mfma_f32_16x16x32_f16(afh[ti], bh, acc1[ti][tj], 0, 0, 0);
                acc2[ti][tj] = __builtin_amdgcn_mfma_f32_16x16x32_f16(afh[ti], bl, acc2[ti][tj], 0, 0, 0);
                acc2[ti][tj] = __builtin_amdgcn_mfma_f32_16x16x32_f16(afl[ti], bh, acc2[ti][tj], 0, 0, 0);
            }
        }
        __syncthreads();
    }

    // element (ti,tj,r): n_local = wave*32 + ti*16 + quad*4 + r ; m_local = tj*16 + l15
    if (!PB) {
        float rp[8] = {0.f}, cp[8] = {0.f};
#pragma unroll
        for (int ti = 0; ti < 2; ++ti)
#pragma unroll
            for (int tj = 0; tj < 8; ++tj)
#pragma unroll
                for (int r = 0; r < 4; ++r) {
                    float dot = fmaf(acc2[ti][tj][r], 2.44140625e-4f, acc1[ti][tj][r]);
                    float e = __expf(fmaf(20.f, dot, -20.f));
                    rp[ti * 4 + r] += e;
                    cp[tj] += e;
                }
#pragma unroll
        for (int i = 0; i < 8; ++i)
#pragma unroll
            for (int m = 1; m < 16; m <<= 1) rp[i] += __shfl_xor(rp[i], m, 64);
        if (l15 == 0) {
#pragma unroll
            for (int ti = 0; ti < 2; ++ti)
#pragma unroll
                for (int r = 0; r < 4; ++r)
                    rowsumP[(size_t)(bb * 32 + mt) * Nn + n0 + wave * 32 + ti * 16 + quad * 4 + r] = rp[ti * 4 + r];
        }
#pragma unroll
        for (int tj = 0; tj < 8; ++tj) {
            cp[tj] += __shfl_xor(cp[tj], 16, 64);
            cp[tj] += __shfl_xor(cp[tj], 32, 64);
        }
        if (quad == 0) {
#pragma unroll
            for (int tj = 0; tj < 8; ++tj) atomicAdd(&colp[tj * 16 + l15], cp[tj]);
        }
        __syncthreads();
        if (t < 128) colsumP[(size_t)(bb * 32 + nt) * Mm + m0 + t] = colp[t];
    } else {
        float Lr[8];
#pragma unroll
        for (int ti = 0; ti < 2; ++ti)
#pragma unroll
            for (int r = 0; r < 4; ++r)
                Lr[ti * 4 + r] = shL[wave * 32 + ti * 16 + quad * 4 + r];

        float bk[8], bc[8];
        int bm[8];
        unsigned cu[8];
#pragma unroll
        for (int i = 0; i < 8; i++) { bk[i] = -INFINITY; bc[i] = -INFINITY; bm[i] = 0x7fffffff; }
#pragma unroll
        for (int j = 0; j < 8; j++) cu[j] = 0u;

#pragma unroll
        for (int ti = 0; ti < 2; ++ti)
#pragma unroll
            for (int tj = 0; tj < 8; ++tj)
#pragma unroll
                for (int r = 0; r < 4; ++r) {
                    float dot = fmaf(acc2[ti][tj][r], 2.44140625e-4f, acc1[ti][tj][r]);
                    float cv = fmaf(40.f, dot, -40.f - Lr[ti * 4 + r]);
                    float kv = cv - shLc[tj * 16 + l15];
                    const int i = ti * 4 + r;
                    if (kv > bk[i]) { bk[i] = kv; bm[i] = m0 + tj * 16 + l15; bc[i] = cv; }
                    unsigned e = encf(cv);
                    if (e > cu[tj]) cu[tj] = e;
                }
#pragma unroll
        for (int i = 0; i < 8; ++i) {
#pragma unroll
            for (int m = 1; m < 16; m <<= 1) {
                float okv = __shfl_xor(bk[i], m, 64);
                int   om  = __shfl_xor(bm[i], m, 64);
                float ocv = __shfl_xor(bc[i], m, 64);
                if (okv > bk[i] || (okv == bk[i] && om < bm[i])) { bk[i] = okv; bm[i] = om; bc[i] = ocv; }
            }
        }
        if (l15 == 0) {
#pragma unroll
            for (int ti = 0; ti < 2; ++ti)
#pragma unroll
                for (int r = 0; r < 4; ++r) {
                    const int i = ti * 4 + r;
                    size_t idx = (size_t)(bb * 32 + mt) * Nn + n0 + wave * 32 + ti * 16 + quad * 4 + r;
                    rkey[idx] = bk[i]; rmArr[idx] = bm[i]; rcvArr[idx] = bc[i];
                }
        }
#pragma unroll
        for (int tj = 0; tj < 8; ++tj) {
            unsigned o = __shfl_xor(cu[tj], 16, 64); if (o > cu[tj]) cu[tj] = o;
            o = __shfl_xor(cu[tj], 32, 64); if (o > cu[tj]) cu[tj] = o;
        }
        if (quad == 0) {
#pragma unroll
            for (int tj = 0; tj < 8; ++tj) atomicMax(&colu[tj * 16 + l15], cu[tj]);
        }
        __syncthreads();
        if (t < 128) cmU[(size_t)(bb * 32 + nt) * Mm + m0 + t] = colu[t];
    }
}

// ---------------- reduce partials -> L = log(rowsum), Lc = log(colsum) ----------------
__global__ __launch_bounds__(256) void logsum_kernel(
    const float* __restrict__ rowsumP, const float* __restrict__ colsumP,
    float* __restrict__ Lrow, float* __restrict__ Lcol)
{
    int t = blockIdx.x * 256 + threadIdx.x;   // 0..32767
    int which = t >> 14;
    int idx = t & 16383;
    int bb = idx >> 12, n = idx & 4095;
    const float* P = which ? colsumP : rowsumP;
    float s = 0.f;
    for (int mt = 0; mt < 32; ++mt) s += P[(size_t)(bb * 32 + mt) * 4096 + n];
    (which ? Lcol : Lrow)[idx] = logf(s);
}

// ---------------- finalize rows: j, valid1 ----------------
__global__ __launch_bounds__(256) void finalize_kernel(
    const float* __restrict__ rkey, const int* __restrict__ rmArr,
    const float* __restrict__ rcvArr, const unsigned* __restrict__ cmU,
    float* __restrict__ outJ, int* __restrict__ jIdx, int* __restrict__ v1)
{
    const float LOG_THR = -4.605170185988091f;   // ln(0.01)
    int p = blockIdx.x * 256 + threadIdx.x;      // 0..16383
    int bb = p >> 12, n = p & 4095;
    float bk = -INFINITY, bc = -INFINITY;
    int bm = 0;
    for (int mt = 0; mt < 32; ++mt) {
        size_t idx = (size_t)(bb * 32 + mt) * Nn + n;
        float k = rkey[idx];
        if (k > bk) { bk = k; bm = rmArr[idx]; bc = rcvArr[idx]; }
    }
    unsigned u = 0u;
    for (int nt = 0; nt < 32; ++nt) {
        unsigned c = cmU[(size_t)(bb * 32 + nt) * Mm + bm];
        if (c > u) u = c;
    }
    float cm = decf(u);
    int ok = (bk > LOG_THR) && (bc >= cm);
    outJ[p] = (float)bm;
    jIdx[p] = bm;
    v1[p]   = ok;
}

// ---------------- affine head: 4 waves/block, one point per wave per iter ----------
__global__ __launch_bounds__(256) void affine_kernel(
    const float* __restrict__ descA, const float* __restrict__ descB,
    const float* __restrict__ kpA, const float* __restrict__ kpB,
    const float* __restrict__ W, const float* __restrict__ bvec,
    const int* __restrict__ jIdx, const int* __restrict__ v1,
    float* __restrict__ outA, float* __restrict__ outB, float* __restrict__ outV)
{
    __shared__ float Ws[D0c * Kc];          // 32 KB
    __shared__ float sbuf[4][4][D0c];       // [wave][{s0A,s1A,s0B,s1B}][128] = 8 KB
    const int t = threadIdx.x, wave = t >> 6, lane = t & 63;
    for (int i = t; i < D0c * Kc; i += 256) Ws[i] = W[i];
    const float bl = bvec[lane];
    __syncthreads();

    float* s0A = sbuf[wave][0];
    float* s1A = sbuf[wave][1];
    float* s0B = sbuf[wave][2];
    float* s1B = sbuf[wave][3];

    for (int p = 0; p < 8; ++p) {
        const int point = blockIdx.x * 32 + wave * 8 + p;
        const int bb = point >> 12;
        const int j = jIdx[point];
        const float* da = descA + (size_t)point * Dd;
        const float* db = descB + (size_t)(bb * Mm + j) * Dd;
        s0A[lane] = da[lane];       s0A[64 + lane] = da[64 + lane];
        s1A[lane] = da[128 + lane]; s1A[64 + lane] = da[192 + lane];
        s0B[lane] = db[lane];       s0B[64 + lane] = db[64 + lane];
        s1B[lane] = db[128 + lane]; s1B[64 + lane] = db[192 + lane];
        __syncthreads();

        float xa = bl, xb = bl;
#pragma unroll 8
        for (int d = 0; d < 128; ++d) {
            float w_ = Ws[d * 64 + lane];
            xa = fmaf(s0A[d], w_, xa);
            xb = fmaf(s0B[d], w_, xb);
        }
        float wa = softplusf(xa), wb = softplusf(xb);
        float w = sqrtf(wa * wb);
        float x0 = s1A[2 * lane], x1 = s1A[2 * lane + 1];
        float y0 = s1B[2 * lane], y1 = s1B[2 * lane + 1];
        float g00 = w * x0 * x0, g01 = w * x0 * x1, g11 = w * x1 * x1;
        float c00 = w * y0 * x0, c01 = w * y0 * x1;
        float c10 = w * y1 * x0, c11 = w * y1 * x1;
#pragma unroll
        for (int m = 32; m; m >>= 1) {
            g00 += __shfl_xor(g00, m, 64); g01 += __shfl_xor(g01, m, 64); g11 += __shfl_xor(g11, m, 64);
            c00 += __shfl_xor(c00, m, 64); c01 += __shfl_xor(c01, m, 64);
            c10 += __shfl_xor(c10, m, 64); c11 += __shfl_xor(c11, m, 64);
        }
        if (lane == 0) {
            g00 += 1e-6f; g11 += 1e-6f;
            float det = g00 * g11 - g01 * g01;
            float e00 = (c00 * g11 - c01 * g01) / det;
            float e01 = (c01 * g00 - c00 * g01) / det;
            float e10 = (c10 * g11 - c11 * g01) / det;
            float e11 = (c11 * g00 - c10 * g01) / det;
            float m00 = e00 * e00 + e10 * e10;
            float m01 = e00 * e01 + e10 * e11;
            float m11 = e01 * e01 + e11 * e11;
            float tr = m00 + m11;
            float dm = m00 * m11 - m01 * m01;
            float disc = sqrtf(fmaxf(0.25f * tr * tr - dm, 0.f));
            float lhi = 0.5f * tr + disc;
            float llo = fmaxf(0.5f * tr - disc, 0.f);
            float shi = sqrtf(lhi), slo = sqrtf(llo);
            float sdet = e00 * e11 - e01 * e10;
            int good = isfinite(shi + slo) && (shi < 3.0f) && (slo > 0.33333334f) && (sdet > 0.f);
            int valid = v1[point] && good;
            outA[2 * point]     = kpA[2 * point];
            outA[2 * point + 1] = kpA[2 * point + 1];
            const float* kb = kpB + (size_t)(bb * Mm + j) * 2;
            outB[2 * point]     = kb[0];
            outB[2 * point + 1] = kb[1];
            outV[point] = valid ? 1.f : 0.f;
        }
        __syncthreads();
    }
}

extern "C" void kernel_launch(void* const* d_in, const int* in_sizes, int n_in,
                              void* d_out, int out_size, void* d_ws, size_t ws_size,
                              hipStream_t stream) {
    const float* kpA = (const float*)d_in[0];
    const float* dA  = (const float*)d_in[1];
    const float* kpB = (const float*)d_in[2];
    const float* dB  = (const float*)d_in[3];
    const float* W   = (const float*)d_in[4];
    const float* bl  = (const float*)d_in[5];
    float* out = (float*)d_out;

    char* ws = (char*)d_ws;
    _Float16* Ah = (_Float16*)ws;  ws += 8388608;
    _Float16* Al = (_Float16*)ws;  ws += 8388608;
    _Float16* Bh = (_Float16*)ws;  ws += 8388608;
    _Float16* Bl = (_Float16*)ws;  ws += 8388608;
    float*    rowsumP = (float*)ws;    ws += 2097152;
    float*    colsumP = (float*)ws;    ws += 2097152;
    float*    rkey    = (float*)ws;    ws += 2097152;
    int*      rmArr   = (int*)ws;      ws += 2097152;
    float*    rcvArr  = (float*)ws;    ws += 2097152;
    unsigned* cmU     = (unsigned*)ws; ws += 2097152;
    float*    Lrow    = (float*)ws;    ws += 65536;
    float*    Lcol    = (float*)ws;    ws += 65536;
    int*      jIdx    = (int*)ws;      ws += 65536;
    int*      v1      = (int*)ws;      ws += 65536;

    float* outA = out;               // matches_A : 32768
    float* outB = out + 32768;       // matches_B : 32768
    float* outJ = out + 65536;       // j (as f32): 16384
    float* outV = out + 81920;       // valid     : 16384

    prep_kernel<<<dim3(4096, 2), 256, 0, stream>>>(dA, dB, Ah, Al, Bh, Bl);
    sim_kernel<0><<<dim3(32, 32, Bb), 256, 0, stream>>>(Ah, Al, Bh, Bl, nullptr, nullptr,
                                                        rowsumP, colsumP,
                                                        nullptr, nullptr, nullptr, nullptr);
    logsum_kernel<<<128, 256, 0, stream>>>(rowsumP, colsumP, Lrow, Lcol);
    sim_kernel<1><<<dim3(32, 32, Bb), 256, 0, stream>>>(Ah, Al, Bh, Bl, Lrow, Lcol,
                                                        nullptr, nullptr,
                                                        rkey, rmArr, rcvArr, cmU);
    finalize_kernel<<<64, 256, 0, stream>>>(rkey, rmArr, rcvArr, cmU, outJ, jIdx, v1);
    affine_kernel<<<512, 256, 0, stream>>>(dA, dB, kpA, kpB, W, bl, jIdx, v1, outA, outB, outV);
}

// Round 5
// 389.997 us; speedup vs baseline: 2.7922x; 1.0340x over previous
//
#include <hip/hip_runtime.h>
#include <math.h>

#define Bb   4
#define Nn   4096
#define Mm   4096
#define Dd   256
#define D0c  128
#define Kc   64

typedef _Float16 half8 __attribute__((ext_vector_type(8)));
typedef float    f32x4 __attribute__((ext_vector_type(4)));

__device__ __forceinline__ unsigned encf(float f) {
    unsigned u = __float_as_uint(f);
    return (u & 0x80000000u) ? ~u : (u | 0x80000000u);
}
__device__ __forceinline__ float decf(unsigned u) {
    return (u & 0x80000000u) ? __uint_as_float(u ^ 0x80000000u) : __uint_as_float(~u);
}
__device__ __forceinline__ float softplusf(float x) {
    return fmaxf(x, 0.f) + log1pf(expf(-fabsf(x)));
}
__device__ __forceinline__ void gl_lds16(const _Float16* g, _Float16* l) {
    __builtin_amdgcn_global_load_lds((const __attribute__((address_space(1))) void*)g,
                                     (__attribute__((address_space(3))) void*)l, 16, 0, 0);
}

// ---------------- prep: normalize rows, split fp16 hi/lo, write TILED layout -------
__global__ __launch_bounds__(256) void prep_kernel(
    const float* __restrict__ dA, const float* __restrict__ dB,
    _Float16* __restrict__ Ah, _Float16* __restrict__ Al,
    _Float16* __restrict__ Bh, _Float16* __restrict__ Bl)
{
    const int t = threadIdx.x, wave = t >> 6, lane = t & 63;
    const int row = blockIdx.x * 4 + wave;           // 0..16383
    const float* src = blockIdx.y ? dB : dA;
    _Float16* dh = blockIdx.y ? Bh : Ah;
    _Float16* dl = blockIdx.y ? Bl : Al;
    const float4 v = *(const float4*)&src[(size_t)row * Dd + lane * 4];
    float ss = v.x * v.x + v.y * v.y + v.z * v.z + v.w * v.w;
#pragma unroll
    for (int m = 32; m; m >>= 1) ss += __shfl_xor(ss, m, 64);
    const float inv = 1.0f / sqrtf(ss);
    float x[4] = {v.x * inv, v.y * inv, v.z * inv, v.w * inv};
    union { _Float16 h[4]; uint2 u; } ph, pl;
#pragma unroll
    for (int i = 0; i < 4; i++) {
        _Float16 h = (_Float16)x[i];
        ph.h[i] = h;
        pl.h[i] = (_Float16)((x[i] - (float)h) * 4096.f);
    }
    const size_t toff = (size_t)(row >> 7) * 32768
                      + (size_t)(lane >> 3) * 4096
                      + (size_t)((lane >> 1) & 3) * 1024
                      + (size_t)(row & 127) * 8 + (lane & 1) * 4;
    *(uint2*)&dh[toff] = ph.u;
    *(uint2*)&dl[toff] = pl.u;
}

// ---------------- MFMA sim kernel ----------------
// PB=0: row/col exp-sum partials (+ optional STORE of dot matrix, non-temporal)
// PB=1: argmax pass (fallback path only)
template<int PB, int STORE>
__global__ __launch_bounds__(256, 2) void sim_kernel(
    const _Float16* __restrict__ Ah, const _Float16* __restrict__ Al,
    const _Float16* __restrict__ Bh, const _Float16* __restrict__ Bl,
    const float* __restrict__ Lrow_g, const float* __restrict__ Lcol_g,
    float* __restrict__ rowsumP, float* __restrict__ colsumP,
    float* __restrict__ rkey, int* __restrict__ rmArr, float* __restrict__ rcvArr,
    unsigned* __restrict__ cmU, float* __restrict__ simG)
{
    __shared__ _Float16 lds[4][4][128][8];   // [comp][koct][row][oct] = 32 KB
    __shared__ float    colp[128];
    __shared__ unsigned colu[128];
    __shared__ float    shL[128], shLc[128];

    const int t = threadIdx.x;
    const int wave = t >> 6, lane = t & 63;
    const int mt = blockIdx.x, nt = blockIdx.y, bb = blockIdx.z;
    const int n0 = nt * 128, m0 = mt * 128;

    if (PB) {
        if (t < 128) {
            shL[t]  = Lrow_g[bb * Nn + n0 + t];
            shLc[t] = Lcol_g[bb * Mm + m0 + t];
            colu[t] = 0u;
        }
    } else {
        if (t < 128) colp[t] = 0.f;
    }

    const _Float16* gb;
    {
        const size_t offA = (size_t)(bb * Nn + n0) * Dd;
        const size_t offB = (size_t)(bb * Mm + m0) * Dd;
        if      (wave == 0) gb = Ah + offA;
        else if (wave == 1) gb = Al + offA;
        else if (wave == 2) gb = Bh + offB;
        else                gb = Bl + offB;
    }

    f32x4 acc1[2][8], acc2[2][8];
#pragma unroll
    for (int ti = 0; ti < 2; ti++)
#pragma unroll
        for (int tj = 0; tj < 8; tj++) { acc1[ti][tj] = (f32x4)0.f; acc2[ti][tj] = (f32x4)0.f; }

    const int quad = lane >> 4, l15 = lane & 15;
    _Float16* ldsw = &lds[wave][0][0][0];

    for (int kc8 = 0; kc8 < 8; ++kc8) {
        const _Float16* gsrc = gb + kc8 * 4096;
#pragma unroll
        for (int q = 0; q < 8; ++q)
            gl_lds16(gsrc + q * 512 + lane * 8, ldsw + q * 512);
        __syncthreads();

        half8 afh[2], afl[2];
        afh[0] = *(const half8*)&lds[0][quad][wave * 32 + l15][0];
        afh[1] = *(const half8*)&lds[0][quad][wave * 32 + 16 + l15][0];
        afl[0] = *(const half8*)&lds[1][quad][wave * 32 + l15][0];
        afl[1] = *(const half8*)&lds[1][quad][wave * 32 + 16 + l15][0];
#pragma unroll
        for (int tj = 0; tj < 8; ++tj) {
            half8 bh = *(const half8*)&lds[2][quad][tj * 16 + l15][0];
            half8 bl = *(const half8*)&lds[3][quad][tj * 16 + l15][0];
#pragma unroll
            for (int ti = 0; ti < 2; ++ti) {
                acc1[ti][tj] = __builtin_amdgcn_mfma_f32_16x16x32_f16(afh[ti], bh, acc1[ti][tj], 0, 0, 0);
                acc2[ti][tj] = __builtin_amdgcn_mfma_f32_16x16x32_f16(afh[ti], bl, acc2[ti][tj], 0, 0, 0);
                acc2[ti][tj] = __builtin_amdgcn_mfma_f32_16x16x32_f16(afl[ti], bh, acc2[ti][tj], 0, 0, 0);
            }
        }
        __syncthreads();
    }

    // element (ti,tj,r): n_local = wave*32 + ti*16 + quad*4 + r ; m_local = tj*16 + l15
    if (!PB) {
        float rp[8] = {0.f}, cp[8] = {0.f};
#pragma unroll
        for (int ti = 0; ti < 2; ++ti)
#pragma unroll
            for (int tj = 0; tj < 8; ++tj)
#pragma unroll
                for (int r = 0; r < 4; ++r) {
                    float dot = fmaf(acc2[ti][tj][r], 2.44140625e-4f, acc1[ti][tj][r]);
                    acc1[ti][tj][r] = dot;                       // keep for optional store
                    float e = __expf(fmaf(20.f, dot, -20.f));
                    rp[ti * 4 + r] += e;
                    cp[tj] += e;
                }
#pragma unroll
        for (int i = 0; i < 8; ++i)
#pragma unroll
            for (int m = 1; m < 16; m <<= 1) rp[i] += __shfl_xor(rp[i], m, 64);
        if (l15 == 0) {
#pragma unroll
            for (int ti = 0; ti < 2; ++ti)
#pragma unroll
                for (int r = 0; r < 4; ++r)
                    rowsumP[(size_t)(bb * 32 + mt) * Nn + n0 + wave * 32 + ti * 16 + quad * 4 + r] = rp[ti * 4 + r];
        }
#pragma unroll
        for (int tj = 0; tj < 8; ++tj) {
            cp[tj] += __shfl_xor(cp[tj], 16, 64);
            cp[tj] += __shfl_xor(cp[tj], 32, 64);
        }
        if (quad == 0) {
#pragma unroll
            for (int tj = 0; tj < 8; ++tj) atomicAdd(&colp[tj * 16 + l15], cp[tj]);
        }
        __syncthreads();
        if (t < 128) colsumP[(size_t)(bb * 32 + nt) * Mm + m0 + t] = colp[t];
        if (STORE) {
            // fire-and-forget nt stores after the last barrier (no drain stall)
            float* base = simG + ((size_t)bb * Nn + n0) * Mm + m0;
#pragma unroll
            for (int ti = 0; ti < 2; ++ti)
#pragma unroll
                for (int r = 0; r < 4; ++r) {
                    float* rowp = base + (size_t)(wave * 32 + ti * 16 + quad * 4 + r) * Mm;
#pragma unroll
                    for (int tj = 0; tj < 8; ++tj)
                        __builtin_nontemporal_store(acc1[ti][tj][r], rowp + tj * 16 + l15);
                }
        }
    } else {
        float Lr[8];
#pragma unroll
        for (int ti = 0; ti < 2; ++ti)
#pragma unroll
            for (int r = 0; r < 4; ++r)
                Lr[ti * 4 + r] = shL[wave * 32 + ti * 16 + quad * 4 + r];

        float bk[8], bc[8];
        int bm[8];
        unsigned cu[8];
#pragma unroll
        for (int i = 0; i < 8; i++) { bk[i] = -INFINITY; bc[i] = -INFINITY; bm[i] = 0x7fffffff; }
#pragma unroll
        for (int j = 0; j < 8; j++) cu[j] = 0u;

#pragma unroll
        for (int ti = 0; ti < 2; ++ti)
#pragma unroll
            for (int tj = 0; tj < 8; ++tj)
#pragma unroll
                for (int r = 0; r < 4; ++r) {
                    float dot = fmaf(acc2[ti][tj][r], 2.44140625e-4f, acc1[ti][tj][r]);
                    float cv = fmaf(40.f, dot, -40.f - Lr[ti * 4 + r]);
                    float kv = cv - shLc[tj * 16 + l15];
                    const int i = ti * 4 + r;
                    if (kv > bk[i]) { bk[i] = kv; bm[i] = m0 + tj * 16 + l15; bc[i] = cv; }
                    unsigned e = encf(cv);
                    if (e > cu[tj]) cu[tj] = e;
                }
#pragma unroll
        for (int i = 0; i < 8; ++i) {
#pragma unroll
            for (int m = 1; m < 16; m <<= 1) {
                float okv = __shfl_xor(bk[i], m, 64);
                int   om  = __shfl_xor(bm[i], m, 64);
                float ocv = __shfl_xor(bc[i], m, 64);
                if (okv > bk[i] || (okv == bk[i] && om < bm[i])) { bk[i] = okv; bm[i] = om; bc[i] = ocv; }
            }
        }
        if (l15 == 0) {
#pragma unroll
            for (int ti = 0; ti < 2; ++ti)
#pragma unroll
                for (int r = 0; r < 4; ++r) {
                    const int i = ti * 4 + r;
                    size_t idx = (size_t)(bb * 32 + mt) * Nn + n0 + wave * 32 + ti * 16 + quad * 4 + r;
                    rkey[idx] = bk[i]; rmArr[idx] = bm[i]; rcvArr[idx] = bc[i];
                }
        }
#pragma unroll
        for (int tj = 0; tj < 8; ++tj) {
            unsigned o = __shfl_xor(cu[tj], 16, 64); if (o > cu[tj]) cu[tj] = o;
            o = __shfl_xor(cu[tj], 32, 64); if (o > cu[tj]) cu[tj] = o;
        }
        if (quad == 0) {
#pragma unroll
            for (int tj = 0; tj < 8; ++tj) atomicMax(&colu[tj * 16 + l15], cu[tj]);
        }
        __syncthreads();
        if (t < 128) cmU[(size_t)(bb * 32 + nt) * Mm + m0 + t] = colu[t];
    }
}

// ---------------- reduce partials -> L = log(rowsum), Lc = log(colsum) ----------------
__global__ __launch_bounds__(256) void logsum_kernel(
    const float* __restrict__ rowsumP, const float* __restrict__ colsumP,
    float* __restrict__ Lrow, float* __restrict__ Lcol)
{
    int t = blockIdx.x * 256 + threadIdx.x;   // 0..32767
    int which = t >> 14;
    int idx = t & 16383;
    int bb = idx >> 12, n = idx & 4095;
    const float* P = which ? colsumP : rowsumP;
    float s = 0.f;
    for (int mt = 0; mt < 32; ++mt) s += P[(size_t)(bb * 32 + mt) * 4096 + n];
    (which ? Lcol : Lrow)[idx] = logf(s);
}

// ---------------- scan pass: wave-per-row argmax + stripe colmax (stored-sim path) ---
__global__ __launch_bounds__(256, 2) void scan_kernel(
    const float* __restrict__ simG,
    const float* __restrict__ Lrow, const float* __restrict__ Lcol,
    float* __restrict__ kvR, float* __restrict__ cvR, int* __restrict__ jR,
    float* __restrict__ colPart)
{
    const int t = threadIdx.x, wave = t >> 6, lane = t & 63;
    const int stripe_g = blockIdx.x * 4 + wave;     // 0..2047
    const int bb = stripe_g >> 9, sb = stripe_g & 511;
    const int row0 = sb * 8;

    f32x4 Lc4[16], cmax[16];
    const float* LcB = Lcol + bb * Mm;
#pragma unroll
    for (int c = 0; c < 16; ++c) {
        Lc4[c] = *(const f32x4*)&LcB[4 * (c * 64 + lane)];
        cmax[c] = (f32x4)(-INFINITY);
    }

    for (int r = 0; r < 8; ++r) {
        const int n = bb * Nn + row0 + r;
        const float* rowp = simG + (size_t)n * Mm;
        const float Ln = Lrow[n];
        const float cbias = -40.f - Ln;
        float bk = -INFINITY, bc = -INFINITY;
        int bm = 0x7fffffff;
#pragma unroll 4
        for (int c = 0; c < 16; ++c) {
            f32x4 s4 = __builtin_nontemporal_load((const f32x4*)&rowp[4 * (c * 64 + lane)]);
            float cv0 = fmaf(40.f, s4.x, cbias);
            float cv1 = fmaf(40.f, s4.y, cbias);
            float cv2 = fmaf(40.f, s4.z, cbias);
            float cv3 = fmaf(40.f, s4.w, cbias);
            cmax[c].x = fmaxf(cmax[c].x, cv0);
            cmax[c].y = fmaxf(cmax[c].y, cv1);
            cmax[c].z = fmaxf(cmax[c].z, cv2);
            cmax[c].w = fmaxf(cmax[c].w, cv3);
            const int mb = 4 * (c * 64 + lane);
            float kv0 = cv0 - Lc4[c].x;
            float kv1 = cv1 - Lc4[c].y;
            float kv2 = cv2 - Lc4[c].z;
            float kv3 = cv3 - Lc4[c].w;
            if (kv0 > bk) { bk = kv0; bm = mb;     bc = cv0; }
            if (kv1 > bk) { bk = kv1; bm = mb + 1; bc = cv1; }
            if (kv2 > bk) { bk = kv2; bm = mb + 2; bc = cv2; }
            if (kv3 > bk) { bk = kv3; bm = mb + 3; bc = cv3; }
        }
#pragma unroll
        for (int sh = 1; sh < 64; sh <<= 1) {
            float okv = __shfl_xor(bk, sh, 64);
            int   om  = __shfl_xor(bm, sh, 64);
            float ocv = __shfl_xor(bc, sh, 64);
            if (okv > bk || (okv == bk && om < bm)) { bk = okv; bm = om; bc = ocv; }
        }
        if (lane == 0) { kvR[n] = bk; cvR[n] = bc; jR[n] = bm; }
    }
    float* cp = colPart + ((size_t)bb * 512 + sb) * Mm;
#pragma unroll
    for (int c = 0; c < 16; ++c)
        *(f32x4*)&cp[4 * (c * 64 + lane)] = cmax[c];
}

// ---------------- column reduce: colMax[bb][m] = max over stripes ----------------
__global__ __launch_bounds__(256) void colreduce_kernel(
    const float* __restrict__ colPart, float* __restrict__ colMax)
{
    const int t = blockIdx.x * 256 + threadIdx.x;   // 0..16383
    const int bb = t >> 12, m = t & 4095;
    float mx = -INFINITY;
    const float* p = colPart + (size_t)bb * 512 * Mm + m;
#pragma unroll 8
    for (int s = 0; s < 512; ++s) mx = fmaxf(mx, p[(size_t)s * Mm]);
    colMax[t] = mx;
}

// ---------------- validate rows (stored-sim path) ----------------
__global__ __launch_bounds__(256) void validate_kernel(
    const float* __restrict__ kvR, const float* __restrict__ cvR,
    const int* __restrict__ jR, const float* __restrict__ colMax,
    float* __restrict__ outJ, int* __restrict__ v1)
{
    const float LOG_THR = -4.605170185988091f;   // ln(0.01)
    const int p = blockIdx.x * 256 + threadIdx.x;    // 0..16383
    const int bb = p >> 12;
    const int j = jR[p];
    const float kv = kvR[p], cv = cvR[p];
    const int ok = (kv > LOG_THR) && (cv >= colMax[bb * Mm + j]);
    outJ[p] = (float)j;
    v1[p] = ok;
}

// ---------------- finalize rows (fallback path) ----------------
__global__ __launch_bounds__(256) void finalize_kernel(
    const float* __restrict__ rkey, const int* __restrict__ rmArr,
    const float* __restrict__ rcvArr, const unsigned* __restrict__ cmU,
    float* __restrict__ outJ, int* __restrict__ jIdx, int* __restrict__ v1)
{
    const float LOG_THR = -4.605170185988091f;   // ln(0.01)
    int p = blockIdx.x * 256 + threadIdx.x;      // 0..16383
    int bb = p >> 12, n = p & 4095;
    float bk = -INFINITY, bc = -INFINITY;
    int bm = 0;
    for (int mt = 0; mt < 32; ++mt) {
        size_t idx = (size_t)(bb * 32 + mt) * Nn + n;
        float k = rkey[idx];
        if (k > bk) { bk = k; bm = rmArr[idx]; bc = rcvArr[idx]; }
    }
    unsigned u = 0u;
    for (int nt = 0; nt < 32; ++nt) {
        unsigned c = cmU[(size_t)(bb * 32 + nt) * Mm + bm];
        if (c > u) u = c;
    }
    float cm = decf(u);
    int ok = (bk > LOG_THR) && (bc >= cm);
    outJ[p] = (float)bm;
    jIdx[p] = bm;
    v1[p]   = ok;
}

// ---------------- affine head: 4 waves/block, one point per wave per iter ----------
__global__ __launch_bounds__(256) void affine_kernel(
    const float* __restrict__ descA, const float* __restrict__ descB,
    const float* __restrict__ kpA, const float* __restrict__ kpB,
    const float* __restrict__ W, const float* __restrict__ bvec,
    const int* __restrict__ jIdx, const int* __restrict__ v1,
    float* __restrict__ outA, float* __restrict__ outB, float* __restrict__ outV)
{
    __shared__ float Ws[D0c * Kc];          // 32 KB
    __shared__ float sbuf[4][4][D0c];       // [wave][{s0A,s1A,s0B,s1B}][128] = 8 KB
    const int t = threadIdx.x, wave = t >> 6, lane = t & 63;
    for (int i = t; i < D0c * Kc; i += 256) Ws[i] = W[i];
    const float bl = bvec[lane];
    __syncthreads();

    float* s0A = sbuf[wave][0];
    float* s1A = sbuf[wave][1];
    float* s0B = sbuf[wave][2];
    float* s1B = sbuf[wave][3];

    for (int p = 0; p < 8; ++p) {
        const int point = blockIdx.x * 32 + wave * 8 + p;
        const int bb = point >> 12;
        const int j = jIdx[point];
        const float* da = descA + (size_t)point * Dd;
        const float* db = descB + (size_t)(bb * Mm + j) * Dd;
        s0A[lane] = da[lane];       s0A[64 + lane] = da[64 + lane];
        s1A[lane] = da[128 + lane]; s1A[64 + lane] = da[192 + lane];
        s0B[lane] = db[lane];       s0B[64 + lane] = db[64 + lane];
        s1B[lane] = db[128 + lane]; s1B[64 + lane] = db[192 + lane];
        __syncthreads();

        float xa = bl, xb = bl;
#pragma unroll 8
        for (int d = 0; d < 128; ++d) {
            float w_ = Ws[d * 64 + lane];
            xa = fmaf(s0A[d], w_, xa);
            xb = fmaf(s0B[d], w_, xb);
        }
        float wa = softplusf(xa), wb = softplusf(xb);
        float w = sqrtf(wa * wb);
        float x0 = s1A[2 * lane], x1 = s1A[2 * lane + 1];
        float y0 = s1B[2 * lane], y1 = s1B[2 * lane + 1];
        float g00 = w * x0 * x0, g01 = w * x0 * x1, g11 = w * x1 * x1;
        float c00 = w * y0 * x0, c01 = w * y0 * x1;
        float c10 = w * y1 * x0, c11 = w * y1 * x1;
#pragma unroll
        for (int m = 32; m; m >>= 1) {
            g00 += __shfl_xor(g00, m, 64); g01 += __shfl_xor(g01, m, 64); g11 += __shfl_xor(g11, m, 64);
            c00 += __shfl_xor(c00, m, 64); c01 += __shfl_xor(c01, m, 64);
            c10 += __shfl_xor(c10, m, 64); c11 += __shfl_xor(c11, m, 64);
        }
        if (lane == 0) {
            g00 += 1e-6f; g11 += 1e-6f;
            float det = g00 * g11 - g01 * g01;
            float e00 = (c00 * g11 - c01 * g01) / det;
            float e01 = (c01 * g00 - c00 * g01) / det;
            float e10 = (c10 * g11 - c11 * g01) / det;
            float e11 = (c11 * g00 - c10 * g01) / det;
            float m00 = e00 * e00 + e10 * e10;
            float m01 = e00 * e01 + e10 * e11;
            float m11 = e01 * e01 + e11 * e11;
            float tr = m00 + m11;
            float dm = m00 * m11 - m01 * m01;
            float disc = sqrtf(fmaxf(0.25f * tr * tr - dm, 0.f));
            float lhi = 0.5f * tr + disc;
            float llo = fmaxf(0.5f * tr - disc, 0.f);
            float shi = sqrtf(lhi), slo = sqrtf(llo);
            float sdet = e00 * e11 - e01 * e10;
            int good = isfinite(shi + slo) && (shi < 3.0f) && (slo > 0.33333334f) && (sdet > 0.f);
            int valid = v1[point] && good;
            outA[2 * point]     = kpA[2 * point];
            outA[2 * point + 1] = kpA[2 * point + 1];
            const float* kb = kpB + (size_t)(bb * Mm + j) * 2;
            outB[2 * point]     = kb[0];
            outB[2 * point + 1] = kb[1];
            outV[point] = valid ? 1.f : 0.f;
        }
        __syncthreads();
    }
}

extern "C" void kernel_launch(void* const* d_in, const int* in_sizes, int n_in,
                              void* d_out, int out_size, void* d_ws, size_t ws_size,
                              hipStream_t stream) {
    const float* kpA = (const float*)d_in[0];
    const float* dA  = (const float*)d_in[1];
    const float* kpB = (const float*)d_in[2];
    const float* dB  = (const float*)d_in[3];
    const float* W   = (const float*)d_in[4];
    const float* bl  = (const float*)d_in[5];
    float* out = (float*)d_out;

    char* ws = (char*)d_ws;
    _Float16* Ah = (_Float16*)ws;  ws += 8388608;
    _Float16* Al = (_Float16*)ws;  ws += 8388608;
    _Float16* Bh = (_Float16*)ws;  ws += 8388608;
    _Float16* Bl = (_Float16*)ws;  ws += 8388608;
    float*    rowsumP = (float*)ws;    ws += 2097152;
    float*    colsumP = (float*)ws;    ws += 2097152;
    float*    Lrow    = (float*)ws;    ws += 65536;
    float*    Lcol    = (float*)ws;    ws += 65536;
    int*      jIdx    = (int*)ws;      ws += 65536;
    int*      v1      = (int*)ws;      ws += 65536;
    float*    kvR     = (float*)ws;    ws += 65536;
    float*    cvR     = (float*)ws;    ws += 65536;
    float*    colMax  = (float*)ws;    ws += 65536;
    char*     big     = ws;            // shared region: new path vs fallback

    // new path layout
    float* simG    = (float*)big;                      // 268,435,456 B
    float* colPart = (float*)(big + 268435456);        //  33,554,432 B
    const size_t need_new = (size_t)(big - (char*)d_ws) + 268435456 + 33554432;

    // fallback layout (overlays simG region)
    float*    rkey  = (float*)big;
    int*      rmArr = (int*)(big + 2097152);
    float*    rcvArr= (float*)(big + 4194304);
    unsigned* cmU   = (unsigned*)(big + 6291456);

    float* outA = out;               // matches_A : 32768
    float* outB = out + 32768;       // matches_B : 32768
    float* outJ = out + 65536;       // j (as f32): 16384
    float* outV = out + 81920;       // valid     : 16384

    prep_kernel<<<dim3(4096, 2), 256, 0, stream>>>(dA, dB, Ah, Al, Bh, Bl);

    if (ws_size >= need_new) {
        sim_kernel<0, 1><<<dim3(32, 32, Bb), 256, 0, stream>>>(Ah, Al, Bh, Bl, nullptr, nullptr,
                                                               rowsumP, colsumP,
                                                               nullptr, nullptr, nullptr, nullptr, simG);
        logsum_kernel<<<128, 256, 0, stream>>>(rowsumP, colsumP, Lrow, Lcol);
        scan_kernel<<<512, 256, 0, stream>>>(simG, Lrow, Lcol, kvR, cvR, jIdx, colPart);
        colreduce_kernel<<<64, 256, 0, stream>>>(colPart, colMax);
        validate_kernel<<<64, 256, 0, stream>>>(kvR, cvR, jIdx, colMax, outJ, v1);
    } else {
        sim_kernel<0, 0><<<dim3(32, 32, Bb), 256, 0, stream>>>(Ah, Al, Bh, Bl, nullptr, nullptr,
                                                               rowsumP, colsumP,
                                                               nullptr, nullptr, nullptr, nullptr, nullptr);
        logsum_kernel<<<128, 256, 0, stream>>>(rowsumP, colsumP, Lrow, Lcol);
        sim_kernel<1, 0><<<dim3(32, 32, Bb), 256, 0, stream>>>(Ah, Al, Bh, Bl, Lrow, Lcol,
                                                               nullptr, nullptr,
                                                               rkey, rmArr, rcvArr, cmU, nullptr);
        finalize_kernel<<<64, 256, 0, stream>>>(rkey, rmArr, rcvArr, cmU, outJ, jIdx, v1);
    }
    affine_kernel<<<512, 256, 0, stream>>>(dA, dB, kpA, kpB, W, bl, jIdx, v1, outA, outB, outV);
}